// Round 8
// baseline (1009.862 us; speedup 1.0000x reference)
//
#include <hip/hip_runtime.h>

#define LRELU_SLOPE 0.01f
#define NEG_BIG -1e10f

typedef unsigned short ushort_t;
typedef __bf16 bf16x8 __attribute__((ext_vector_type(8)));
typedef float f32x4 __attribute__((ext_vector_type(4)));

static __device__ __forceinline__ float lrelu_f(float x) {
    return x >= 0.0f ? x : LRELU_SLOPE * x;
}

static __device__ __forceinline__ ushort_t f2bf(float f) {
    unsigned int u = __float_as_uint(f);
    u += 0x7fffu + ((u >> 16) & 1u);
    return (ushort_t)(u >> 16);
}

static __device__ __forceinline__ void gld_lds16(const ushort_t* g, ushort_t* l) {
    __builtin_amdgcn_global_load_lds((const __attribute__((address_space(1))) void*)g,
                                     (__attribute__((address_space(3))) void*)l,
                                     16, 0, 0);
}

// ---------------------------------------------------------------------------
// NT bf16 MFMA GEMM: C[m,n] = epi( sum_k A[m,k] * B[n,k] )
// B-RESIDENT / A-STREAMING design (R7): R2/R4/R5/R6 all null at ~86us with
// every pipe <33% busy -> the invariant was the LDS-staged-A path with a
// block-wide drain every BK. This kernel removes it:
//   BM=512 x BN=64, 8 waves (8M x 1N), per-wave out 64x64.
//   B panel (64 rows x K<=512) = 64 KB staged into LDS ONCE (one barrier),
//   then the K-loop is 16 barrier-free steps of
//     {4 global bf16x8 A-loads -> VGPR, 4 ds_read_b128 B-frags, 16 MFMA}.
//   No syncthreads, no vmcnt drains in the loop: compiler pipelines loads
//   across iterations; 16 independent waves/CU (2 blocks x 8) hide latency.
// A-coalescing: lane group q=0..3 reads 64B contiguous per row (16 rows/instr).
// A-reuse: 8 col-tiles share an A row-panel; grid x = N-tiles keeps them
// lin-consecutive -> same XCD under the remap -> A HBM-fetched once, L2 8x.
// B LDS swizzle: 16B-chunk c of row r stored at position c ^ (r&7);
// staging uses per-lane source chunk (lane ^ (r&7)) with linear dest
// (rule #21 both-sides); ds_read pos = (ks*4+q) ^ (lr&7) -> 2-way max (free).
// K=1024 (step 8): two 512-chunks, chunk ch reads A0/A1 (Ksplit==512 in all
// launches), B re-staged per chunk with one barrier between.
// Occupancy: acc 64 + frags 32 + addr ~= 110 regs, cap 128 (512,4) ->
// 2 blocks/CU (LDS 2x64KB), 16 waves/CU.
// XCD-aware tile remap (R0): lin -> (lin%8)*(nwg/8)+lin/8.
// RM mask: row < Mhalf ? rm1[row] : rm2[row-Mhalf]  (combined-M launches)
// PM mask: rm1[bz*M+row] && rm2[bz*N+col] else += NEG_BIG (batched score GEMM)
// TWOUT: also store bf16 transposed per-batch with slot swap:
//   CT[(((row>>9)+64)&127)*S + col*512 + (row&511)]  -> [r2mT | r1mT] order
// ---------------------------------------------------------------------------
template<bool BIAS, bool LRELU, bool RM, bool PM, bool BF16OUT, bool TWOUT>
__global__ __launch_bounds__(512, 4)
void gemm_nt(const ushort_t* __restrict__ A0, const ushort_t* __restrict__ A1,
             int Ksplit, int lda0, int lda1,
             const ushort_t* __restrict__ B, int ldb,
             const float* __restrict__ bias,
             const int* __restrict__ rm1, const int* __restrict__ rm2,
             void* __restrict__ C, int ldc,
             ushort_t* __restrict__ CT, int Mhalf,
             int M, int N, int K,
             long sA, long sB, long sC)
{
    __shared__ ushort_t Bs[64 * 512];   // 64 KB, row-major, chunk-swizzled

    // XCD-aware block remap (see header comment)
    const unsigned nbx = gridDim.x, nby = gridDim.y;
    unsigned lin = blockIdx.x + nbx * (blockIdx.y + nby * blockIdx.z);
    const unsigned nwg = nbx * nby * gridDim.z;
    if ((nwg & 7u) == 0u)
        lin = (lin & 7u) * (nwg >> 3) + (lin >> 3);
    const unsigned bxs = lin % nbx;
    const unsigned t1  = lin / nbx;
    const unsigned bys = t1 % nby;
    const unsigned bzs = t1 / nby;

    const int bz   = (int)bzs;
    const int tid  = threadIdx.x;
    const int w    = tid >> 6;         // 0..7 (M slice)
    const int lane = tid & 63;
    const int row0 = (int)bys * 512;
    const int col0 = (int)bxs * 64;

    const int lr = lane & 15, q = lane >> 4;
    const int wrow = row0 + w * 64;

    const ushort_t* Bb = B + (long)bz * sB;

    f32x4 acc[4][4] = {};

    const int nch = K >> 9;            // number of 512-wide K chunks (1 or 2)
    for (int ch = 0; ch < nch; ++ch) {
        const ushort_t* Ap = (ch == 0) ? A0 + (long)bz * sA : A1 + (long)bz * sA;
        const int lda = (ch == 0) ? lda0 : lda1;
        const int kb  = ch << 9;

        if (ch) {   // all waves' reads of the previous B chunk are in regs
            __builtin_amdgcn_s_barrier();
            asm volatile("" ::: "memory");
        }
        // stage B panel chunk: wave w stages rows w*8..w*8+8, 1 row/gld_lds;
        // dest linear (lane -> chunk position lane), source chunk lane^(r&7)
        #pragma unroll
        for (int r = 0; r < 8; ++r) {
            const int brow = w * 8 + r;
            gld_lds16(Bb + (size_t)(col0 + brow) * ldb + kb + ((lane ^ (r & 7)) * 8),
                      &Bs[brow * 512]);
        }
        asm volatile("s_waitcnt vmcnt(0)" ::: "memory");
        __builtin_amdgcn_s_barrier();
        asm volatile("" ::: "memory");

        // barrier-free K loop: 16 steps of {4 A-loads, 4 B ds_reads, 16 MFMA}
        #pragma unroll
        for (int ks = 0; ks < 16; ++ks) {
            bf16x8 af[4], bf[4];
            #pragma unroll
            for (int ii = 0; ii < 4; ++ii)
                af[ii] = *reinterpret_cast<const bf16x8*>(
                    &Ap[(size_t)(wrow + ii * 16 + lr) * lda + ks * 32 + q * 8]);
            #pragma unroll
            for (int jj = 0; jj < 4; ++jj)
                bf[jj] = *reinterpret_cast<const bf16x8*>(
                    &Bs[(jj * 16 + lr) * 512 + (((ks * 4 + q) ^ (lr & 7)) * 8)]);
            #pragma unroll
            for (int ii = 0; ii < 4; ++ii)
                #pragma unroll
                for (int jj = 0; jj < 4; ++jj)
                    acc[ii][jj] = __builtin_amdgcn_mfma_f32_16x16x32_bf16(
                        af[ii], bf[jj], acc[ii][jj], 0, 0, 0);
        }
    }

    float biasv[4];
    int mj[4];
    #pragma unroll
    for (int j = 0; j < 4; ++j) {
        const int c = col0 + j * 16 + lr;
        if (BIAS) biasv[j] = bias[c];
        if (PM)   mj[j] = rm2[(long)bz * N + c];
    }
    float* Cf = (float*)C + (long)bz * sC;
    ushort_t* Ch = (ushort_t*)C + (long)bz * sC;

    #pragma unroll
    for (int i = 0; i < 4; ++i) {
        const int rg0 = wrow + i * 16 + q * 4;   // first of 4 consecutive rows
        int mi4[4];
        if (RM || PM) {
            #pragma unroll
            for (int r = 0; r < 4; ++r) {
                const int row = rg0 + r;
                if (PM)      mi4[r] = rm1[(long)bz * M + row];
                else         mi4[r] = (row < Mhalf) ? rm1[row] : rm2[row - Mhalf];
            }
        }
        #pragma unroll
        for (int j = 0; j < 4; ++j) {
            const int c = col0 + j * 16 + lr;
            ushort_t tp[4];
            #pragma unroll
            for (int r = 0; r < 4; ++r) {
                const int row = rg0 + r;
                float v = acc[i][j][r];
                if (BIAS) v += biasv[j];
                if (LRELU) v = lrelu_f(v);
                if (RM) v *= (float)mi4[r];
                if (PM) { if (!(mi4[r] && mj[j])) v += NEG_BIG; }
                const size_t a = (size_t)row * ldc + c;
                if (BF16OUT) Ch[a] = f2bf(v); else Cf[a] = v;
                if (TWOUT) tp[r] = f2bf(v);
            }
            if (TWOUT) {
                // slot-swapped: r1 batches -> slots 64..127, r2 batches -> 0..63
                const size_t ta = ((size_t)(((rg0 >> 9) + 64) & 127)) * 262144
                                + (size_t)c * 512 + (rg0 & 511);
                *reinterpret_cast<uint2*>(CT + ta) = *reinterpret_cast<uint2*>(tp);
            }
        }
    }
}

// ---------------------------------------------------------------------------
// fp32 -> bf16 convert for both inputs (y selects tensor)
__global__ __launch_bounds__(256)
void cvt2_f32_bf16(const float* __restrict__ a, const float* __restrict__ b,
                   ushort_t* __restrict__ oa, ushort_t* __restrict__ ob)
{
    const float* in = blockIdx.y ? b : a;
    ushort_t* out = blockIdx.y ? ob : oa;
    const long i = ((long)blockIdx.x * 256 + threadIdx.x) * 4;
    const float4 v = *reinterpret_cast<const float4*>(in + i);
    ushort_t o[4] = { f2bf(v.x), f2bf(v.y), f2bf(v.z), f2bf(v.w) };
    *reinterpret_cast<uint2*>(out + i) = *reinterpret_cast<uint2*>(o);
}

// all 4 weight transposes in one launch: fp32 [R,C] -> bf16 [C,R], z selects
__global__ __launch_bounds__(256)
void transpose_cvt4(const float* __restrict__ W1, const float* __restrict__ W2,
                    const float* __restrict__ Wc1, const float* __restrict__ Wc2,
                    ushort_t* __restrict__ W1t, ushort_t* __restrict__ W2t,
                    ushort_t* __restrict__ Wc1t, ushort_t* __restrict__ Wc2t)
{
    __shared__ float t[32][33];
    const int z = blockIdx.z;
    const float* in = (z == 0) ? W1 : (z == 1) ? W2 : (z == 2) ? Wc1 : Wc2;
    ushort_t* out   = (z == 0) ? W1t : (z == 1) ? W2t : (z == 2) ? Wc1t : Wc2t;
    const int R = (z == 2) ? 1024 : 512;
    const int C = 512;
    const int c0 = blockIdx.x * 32, r0 = blockIdx.y * 32;
    if (r0 >= R) return;
    const int tx = threadIdx.x & 31, ty = threadIdx.x >> 5;
    #pragma unroll
    for (int p = 0; p < 4; ++p)
        t[ty + p * 8][tx] = in[(size_t)(r0 + ty + p * 8) * C + c0 + tx];
    __syncthreads();
    #pragma unroll
    for (int p = 0; p < 4; ++p)
        out[(size_t)(c0 + ty + p * 8) * R + r0 + tx] = f2bf(t[tx][ty + p * 8]);
}

// one wave per row: max + 1/sum(exp)
__global__ __launch_bounds__(256)
void row_stats(const float* __restrict__ o, float* __restrict__ rmax,
               float* __restrict__ rsinv, int L)
{
    const int row  = blockIdx.x * 4 + (threadIdx.x >> 6);
    const int lane = threadIdx.x & 63;
    const float* p = o + (long)row * L;
    float m = -3.0e38f;
    for (int j = lane; j < L; j += 64) m = fmaxf(m, p[j]);
    #pragma unroll
    for (int off = 32; off > 0; off >>= 1) m = fmaxf(m, __shfl_xor(m, off));
    float s = 0.0f;
    for (int j = lane; j < L; j += 64) s += __expf(p[j] - m);
    #pragma unroll
    for (int off = 32; off > 0; off >>= 1) s += __shfl_xor(s, off);
    if (lane == 0) { rmax[row] = m; rsinv[row] = 1.0f / s; }
}

// column stats phase 1: each block scans 64 rows for 256 columns (split-K)
__global__ __launch_bounds__(256)
void col_part(const float* __restrict__ o, float* __restrict__ pm,
              float* __restrict__ ps, int L)
{
    const int b  = blockIdx.z;
    const int rc = blockIdx.y;
    const int j  = blockIdx.x * 256 + threadIdx.x;
    const float* p = o + (long)b * L * L + (long)rc * 64 * L + j;
    float m = -3.0e38f, s = 0.0f;
    #pragma unroll 4
    for (int i = 0; i < 64; ++i) {
        const float x = p[(long)i * L];
        const float mn = fmaxf(m, x);
        s = s * __expf(m - mn) + __expf(x - mn);
        m = mn;
    }
    const long idx = ((long)b * 8 + rc) * L + j;
    pm[idx] = m;
    ps[idx] = s;
}

// column stats phase 2: merge 8 partials per column
__global__ __launch_bounds__(256)
void col_combine(const float* __restrict__ pm, const float* __restrict__ ps,
                 float* __restrict__ cmax, float* __restrict__ csinv, int L)
{
    const int b = blockIdx.y;
    const int j = blockIdx.x * 256 + threadIdx.x;
    float mk[8], sk[8];
    #pragma unroll
    for (int k = 0; k < 8; ++k) {
        mk[k] = pm[((long)b * 8 + k) * L + j];
        sk[k] = ps[((long)b * 8 + k) * L + j];
    }
    float m = -3.0e38f;
    #pragma unroll
    for (int k = 0; k < 8; ++k) m = fmaxf(m, mk[k]);
    float s = 0.0f;
    #pragma unroll
    for (int k = 0; k < 8; ++k) s += sk[k] * __expf(mk[k] - m);
    cmax[b * L + j]  = m;
    csinv[b * L + j] = 1.0f / s;
}

// tiled: o1[b,i,j] = rowsm * mpos (bf16), o2T[b,j,i] = colsm * mpos (bf16)
__global__ __launch_bounds__(256)
void softmax_apply(const float* __restrict__ o,
                   ushort_t* __restrict__ o1, ushort_t* __restrict__ o2T,
                   const float* __restrict__ rmax, const float* __restrict__ rsinv,
                   const float* __restrict__ cmax, const float* __restrict__ csinv,
                   const int* __restrict__ m1, const int* __restrict__ m2)
{
    __shared__ ushort_t t[32][33];
    const int b = blockIdx.z;
    const long bo = (long)b * 512 * 512;
    const int j0 = blockIdx.x * 32, i0 = blockIdx.y * 32;
    const int tx = threadIdx.x & 31, ty = threadIdx.x >> 5;
    const int col = b * 512 + j0 + tx;
    const int mjv = m2[col];
    const float cm = cmax[col], cs = csinv[col];
    #pragma unroll
    for (int p = 0; p < 4; ++p) {
        const int i = i0 + ty + p * 8;
        const int row = b * 512 + i;
        const float x = o[bo + (long)i * 512 + j0 + tx];
        const float mp = (m1[row] != 0 && mjv != 0) ? 1.0f : 0.0f;
        o1[bo + (long)i * 512 + j0 + tx] = f2bf(__expf(x - rmax[row]) * rsinv[row] * mp);
        t[ty + p * 8][tx] = f2bf(__expf(x - cm) * cs * mp);
    }
    __syncthreads();
    #pragma unroll
    for (int p = 0; p < 4; ++p)
        o2T[bo + (long)(j0 + ty + p * 8) * 512 + i0 + tx] = t[tx][ty + p * 8];
}

// ---------------------------------------------------------------------------
extern "C" void kernel_launch(void* const* d_in, const int* in_sizes, int n_in,
                              void* d_out, int out_size, void* d_ws, size_t ws_size,
                              hipStream_t stream)
{
    const float* r1  = (const float*)d_in[0];
    const float* r2  = (const float*)d_in[1];
    const int*   m1  = (const int*)d_in[2];
    const int*   m2  = (const int*)d_in[3];
    const float* W1  = (const float*)d_in[4];
    const float* b1v = (const float*)d_in[5];
    const float* W2  = (const float*)d_in[6];
    const float* b2v = (const float*)d_in[7];
    const float* Wc1 = (const float*)d_in[8];
    const float* bc1 = (const float*)d_in[9];
    const float* Wc2 = (const float*)d_in[10];
    const float* bc2 = (const float*)d_in[11];
    float* out = (float*)d_out;

    constexpr int  Bn = 64, L = 512, D = 512;
    constexpr long CE = (long)Bn * L * D;  // 16,777,216 elements
    constexpr long S  = (long)L * L;       // 262,144
    constexpr int  NR = Bn * L;            // 32,768

    // d_out: 4 bf16 scratch slots (all dead before final fp32 writes)
    ushort_t* O    = (ushort_t*)d_out;
    ushort_t* r1b  = O;            // slot0: r1 bf16 (dead after GEMM 1)
    ushort_t* r2b  = O + CE;       // slot1: r2 bf16
    // After GEMM 2 (TWOUT slot-swapped): [slot0 | slot1] = [r2mT | r1mT],
    // uniform batch stride S from base O for the merged ctx GEMM.
    ushort_t* TT   = O;
    ushort_t* o1b  = O + 2 * CE;   // slot2: o1  (batches 0..63)
    // slot3 = o1b + CE = o2T (batches 64..127 of the same strided array)
    ushort_t* o2Tb = O + 3 * CE;

    // workspace
    char* wsb = (char*)d_ws;
    // R0 [0,4CE): h (2CE ushorts) -> obuf (CE floats) -> r1c‖r2c (2CE ushorts)
    ushort_t* hb   = (ushort_t*)wsb;
    float*    obuf = (float*)wsb;
    ushort_t* r1c  = (ushort_t*)wsb;
    // R1 [4CE,8CE): hc (compare hidden)
    ushort_t* hc   = (ushort_t*)(wsb + 4 * CE);
    // R2 [8CE,12CE): r1m ‖ r2m
    ushort_t* r1mb = (ushort_t*)(wsb + 8 * CE);
    ushort_t* r2mb = (ushort_t*)(wsb + 10 * CE);
    // R3 [12CE, ...): weights + stats
    ushort_t* W1t  = (ushort_t*)(wsb + 12 * CE);
    ushort_t* W2t  = W1t + 512 * 512;
    ushort_t* Wc1t = W2t + 512 * 512;            // [512,1024]
    ushort_t* Wc2t = Wc1t + 512 * 1024;
    float* rmaxv = (float*)(Wc2t + 512 * 512);
    float* rsinv = rmaxv + NR;
    float* cmaxv = rsinv + NR;
    float* csinv = cmaxv + NR;
    float* pmbuf = csinv + NR;                   // 8*512*64 floats
    float* psbuf = pmbuf + 8 * L * Bn;

    const dim3 blk(256);
    const dim3 blkG(512);
    const dim3 gD2(D / 64, 2 * NR / 512, 1);     // combined dense: 8 x 128
    const dim3 gB(L / 64, L / 512, Bn);          // batched score: 8 x 1 x 64
    const dim3 gB2(L / 64, L / 512, 2 * Bn);     // merged ctx: 8 x 1 x 128

    // 0) convert inputs + weights
    cvt2_f32_bf16<<<dim3(CE / 1024, 2), blk, 0, stream>>>(r1, r2, r1b, r2b);
    transpose_cvt4<<<dim3(16, 32, 4), blk, 0, stream>>>(
        W1, W2, Wc1, Wc2, W1t, W2t, Wc1t, Wc2t);

    // 1) h = lrelu([r1;r2] @ W1 + b1)   M=65536
    gemm_nt<true,true,false,false,true,false><<<gD2, blkG, 0, stream>>>(
        r1b, r1b, D, D, D, W1t, D, b1v, nullptr, nullptr, hb, D,
        nullptr, 0, 2 * NR, D, D, 0, 0, 0);
    // 2) [r1m;r2m] = lrelu(h @ W2 + b2) * mask  + fused transposed copies
    gemm_nt<true,true,true,false,true,true><<<gD2, blkG, 0, stream>>>(
        hb, hb, D, D, D, W2t, D, b2v, m1, m2, r1mb, D,
        TT, NR, 2 * NR, D, D, 0, 0, 0);
    // 3) o = r1m @ r2m^T + pairmask  (batched fp32)
    gemm_nt<false,false,false,true,false,false><<<gB, blkG, 0, stream>>>(
        r1mb, r1mb, D, D, D, r2mb, D, nullptr, m1, m2, obuf, L,
        nullptr, 0, L, L, D, S, S, S);
    // 4) softmax stats
    row_stats<<<dim3(NR / 4), blk, 0, stream>>>(obuf, rmaxv, rsinv, L);
    col_part<<<dim3(L / 256, 8, Bn), blk, 0, stream>>>(obuf, pmbuf, psbuf, L);
    col_combine<<<dim3(L / 256, Bn), blk, 0, stream>>>(pmbuf, psbuf, cmaxv, csinv, L);
    // 5) o1 (bf16) + o2^T (bf16)
    softmax_apply<<<dim3(16, 16, Bn), blk, 0, stream>>>(
        obuf, o1b, o2Tb, rmaxv, rsinv, cmaxv, csinv, m1, m2);
    // 6+7 merged) z<64: r1_c = o1 @ r2m^T-slots ; z>=64: r2_c = o2T @ r1m^T-slots
    gemm_nt<false,false,false,false,true,false><<<gB2, blkG, 0, stream>>>(
        o1b, o1b, L, L, L, TT, L, nullptr, nullptr, nullptr, r1c, D,
        nullptr, 0, L, D, L, S, S, S);
    // 8) hc = lrelu(cat([r1m;r2m],[r1c;r2c]) @ Wc1 + bc1)  M=65536, K=1024
    gemm_nt<true,true,false,false,true,false><<<gD2, blkG, 0, stream>>>(
        r1mb, r1c, D, D, D, Wc1t, 2 * D, bc1, nullptr, nullptr, hc, D,
        nullptr, 0, 2 * NR, D, 2 * D, 0, 0, 0);
    // 9) [out1;out2] = lrelu(hc @ Wc2 + bc2) * mask  (fp32, full d_out)
    gemm_nt<true,true,true,false,false,false><<<gD2, blkG, 0, stream>>>(
        hc, hc, D, D, D, Wc2t, D, bc2, m1, m2, out, D,
        nullptr, NR, 2 * NR, D, D, 0, 0, 0);
}